// Round 1
// baseline (685.308 us; speedup 1.0000x reference)
//
#include <hip/hip_runtime.h>
#include <hip/hip_bf16.h>

typedef unsigned short u16;
typedef u16 u16x8 __attribute__((ext_vector_type(8)));
typedef float f32x8 __attribute__((ext_vector_type(8)));

#define IN_DIM 1024
#define H_DIM  2048
#define V_DIM  50257
#define NEG_BIG (-1e30f)

__device__ __forceinline__ float bf2f(u16 u) {
    union { unsigned int i; float f; } v;
    v.i = ((unsigned int)u) << 16;
    return v.f;
}

__device__ __forceinline__ u16 f2bf(float f) {
    union { float f; unsigned int i; } v;
    v.f = f;
    unsigned int i = v.i;
    i += 0x7fffu + ((i >> 16) & 1u);   // round-to-nearest-even
    return (u16)(i >> 16);
}

template<typename T>
__device__ __forceinline__ T ntl(const T* p) { return __builtin_nontemporal_load(p); }

// all-lane butterfly sum across the 64-lane wave
__device__ __forceinline__ float wave_allreduce_sum(float v) {
    #pragma unroll
    for (int d = 32; d; d >>= 1) v += __shfl_xor(v, d, 64);
    return v;
}

__device__ __forceinline__ float sigmoidf(float x) { return 1.f / (1.f + __expf(-x)); }

__device__ __forceinline__ float ld_scalar(const void* p, int i, bool bf) {
    return bf ? bf2f(((const u16*)p)[i]) : ((const float*)p)[i];
}

// ---------------- inline dtype probe: bf16 vs fp32, from x's bit patterns ----------------
// Even-indexed u16 words of a bf16 buffer hold bf16 values of ~N(0,1): exponent field in a
// narrow band (~100% hits). For an fp32 buffer they are low mantissa bits (uniform, ~19%).
// 64 samples per wave; every wave reads the same 64 words -> uniform verdict, no sync needed.
// Max byte offset 253 < 2048, safe for either dtype of x (IN_DIM=1024).
__device__ __forceinline__ bool probe_bf16(const void* x) {
    const u16* p = (const u16*)x;
    const int lane = threadIdx.x & 63;
    u16 w = p[2 * lane];
    int e = (w >> 7) & 0xFF;
    unsigned long long b = __ballot(e >= 0x60 && e <= 0x8F);
    return __popcll(b) > 40;
}

// ---------------- LSTM layer 1 ----------------
// grid = H_DIM blocks x 256 thr (4 waves); wave w computes gate-row w*H_DIM + j.
__global__ __launch_bounds__(256) void lstm1_kernel(
    const void* __restrict__ x, const void* __restrict__ h1, const void* __restrict__ c1,
    const void* __restrict__ W_ih, const void* __restrict__ W_hh,
    const void* __restrict__ b_ih, const void* __restrict__ b_hh,
    float* __restrict__ h_out)
{
    const bool bf  = probe_bf16(x);
    const int j    = blockIdx.x;
    const int wave = threadIdx.x >> 6;
    const int lane = threadIdx.x & 63;
    const int row  = wave * H_DIM + j;

    float acc = 0.f;
    if (bf) {
        // phase 1: W_ih row (1024) . x  — load batch, then FMA
        {
            const u16x8* wp = (const u16x8*)W_ih + (size_t)row * (IN_DIM / 8) + lane;
            const u16x8* vp = (const u16x8*)x + lane;
            u16x8 a[2], v[2];
            #pragma unroll
            for (int k = 0; k < 2; ++k) { a[k] = ntl(wp + 64 * k); v[k] = vp[64 * k]; }
            #pragma unroll
            for (int k = 0; k < 2; ++k)
                #pragma unroll
                for (int t = 0; t < 8; ++t) acc += bf2f(a[k][t]) * bf2f(v[k][t]);
        }
        // phase 2: W_hh row (2048) . h1
        {
            const u16x8* wp = (const u16x8*)W_hh + (size_t)row * (H_DIM / 8) + lane;
            const u16x8* vp = (const u16x8*)h1 + lane;
            u16x8 a[4], v[4];
            #pragma unroll
            for (int k = 0; k < 4; ++k) { a[k] = ntl(wp + 64 * k); v[k] = vp[64 * k]; }
            #pragma unroll
            for (int k = 0; k < 4; ++k)
                #pragma unroll
                for (int t = 0; t < 8; ++t) acc += bf2f(a[k][t]) * bf2f(v[k][t]);
        }
    } else {
        {
            const f32x8* wp = (const f32x8*)W_ih + (size_t)row * (IN_DIM / 8) + lane;
            const f32x8* vp = (const f32x8*)x + lane;
            f32x8 a[2], v[2];
            #pragma unroll
            for (int k = 0; k < 2; ++k) { a[k] = ntl(wp + 64 * k); v[k] = vp[64 * k]; }
            #pragma unroll
            for (int k = 0; k < 2; ++k)
                #pragma unroll
                for (int t = 0; t < 8; ++t) acc += a[k][t] * v[k][t];
        }
        {
            const f32x8* wp = (const f32x8*)W_hh + (size_t)row * (H_DIM / 8) + lane;
            const f32x8* vp = (const f32x8*)h1 + lane;
            f32x8 a[4], v[4];
            #pragma unroll
            for (int k = 0; k < 4; ++k) { a[k] = ntl(wp + 64 * k); v[k] = vp[64 * k]; }
            #pragma unroll
            for (int k = 0; k < 4; ++k)
                #pragma unroll
                for (int t = 0; t < 8; ++t) acc += a[k][t] * v[k][t];
        }
    }
    acc = wave_allreduce_sum(acc);

    __shared__ float gs[4];
    if (lane == 0) gs[wave] = acc + ld_scalar(b_ih, row, bf) + ld_scalar(b_hh, row, bf);
    __syncthreads();
    if (threadIdx.x == 0) {
        float gi = sigmoidf(gs[0]);
        float gf = sigmoidf(gs[1]);
        float gg = tanhf(gs[2]);
        float go = sigmoidf(gs[3]);
        float c  = gf * ld_scalar(c1, j, bf) + gi * gg;
        h_out[j] = go * tanhf(c);
    }
}

// ---------------- LSTM layer 2: input h1n is fp32 in ws ----------------
__global__ __launch_bounds__(256) void lstm2_kernel(
    const void* __restrict__ x,          // probe only
    const float* __restrict__ h1n, const void* __restrict__ h2, const void* __restrict__ c2,
    const void* __restrict__ W_ih, const void* __restrict__ W_hh,
    const void* __restrict__ b_ih, const void* __restrict__ b_hh,
    float* __restrict__ h_out)
{
    const bool bf  = probe_bf16(x);
    const int j    = blockIdx.x;
    const int wave = threadIdx.x >> 6;
    const int lane = threadIdx.x & 63;
    const int row  = wave * H_DIM + j;

    float acc = 0.f;
    if (bf) {
        // phase 1: W_ih row (2048, bf16) . h1n (fp32, f32x8 matches u16x8 element map)
        {
            const u16x8* wp = (const u16x8*)W_ih + (size_t)row * (H_DIM / 8) + lane;
            const f32x8* vp = (const f32x8*)h1n + lane;
            u16x8 a[4]; f32x8 v[4];
            #pragma unroll
            for (int k = 0; k < 4; ++k) { a[k] = ntl(wp + 64 * k); v[k] = vp[64 * k]; }
            #pragma unroll
            for (int k = 0; k < 4; ++k)
                #pragma unroll
                for (int t = 0; t < 8; ++t) acc += bf2f(a[k][t]) * v[k][t];
        }
        // phase 2: W_hh row (2048, bf16) . h2 (bf16)
        {
            const u16x8* wp = (const u16x8*)W_hh + (size_t)row * (H_DIM / 8) + lane;
            const u16x8* vp = (const u16x8*)h2 + lane;
            u16x8 a[4], v[4];
            #pragma unroll
            for (int k = 0; k < 4; ++k) { a[k] = ntl(wp + 64 * k); v[k] = vp[64 * k]; }
            #pragma unroll
            for (int k = 0; k < 4; ++k)
                #pragma unroll
                for (int t = 0; t < 8; ++t) acc += bf2f(a[k][t]) * bf2f(v[k][t]);
        }
    } else {
        {
            const f32x8* wp = (const f32x8*)W_ih + (size_t)row * (H_DIM / 8) + lane;
            const f32x8* vp = (const f32x8*)h1n + lane;
            f32x8 a[4], v[4];
            #pragma unroll
            for (int k = 0; k < 4; ++k) { a[k] = ntl(wp + 64 * k); v[k] = vp[64 * k]; }
            #pragma unroll
            for (int k = 0; k < 4; ++k)
                #pragma unroll
                for (int t = 0; t < 8; ++t) acc += a[k][t] * v[k][t];
        }
        {
            const f32x8* wp = (const f32x8*)W_hh + (size_t)row * (H_DIM / 8) + lane;
            const f32x8* vp = (const f32x8*)h2 + lane;
            f32x8 a[4], v[4];
            #pragma unroll
            for (int k = 0; k < 4; ++k) { a[k] = ntl(wp + 64 * k); v[k] = vp[64 * k]; }
            #pragma unroll
            for (int k = 0; k < 4; ++k)
                #pragma unroll
                for (int t = 0; t < 8; ++t) acc += a[k][t] * v[k][t];
        }
    }
    acc = wave_allreduce_sum(acc);

    __shared__ float gs[4];
    if (lane == 0) gs[wave] = acc + ld_scalar(b_ih, row, bf) + ld_scalar(b_hh, row, bf);
    __syncthreads();
    if (threadIdx.x == 0) {
        float gi = sigmoidf(gs[0]);
        float gf = sigmoidf(gs[1]);
        float gg = tanhf(gs[2]);
        float go = sigmoidf(gs[3]);
        float c  = gf * ld_scalar(c2, j, bf) + gi * gg;
        h_out[j] = go * tanhf(c);
    }
}

// ---------------- logits + per-block online softmax partials ----------------
#define ROWS_PER_WAVE 8
#define ROWS_PER_BLOCK 32
__global__ __launch_bounds__(256) void logits_kernel(
    const void* __restrict__ x,          // probe only
    const float* __restrict__ h2n, const void* __restrict__ W, const void* __restrict__ b,
    float* __restrict__ logits, float* __restrict__ pmax, float* __restrict__ psum)
{
    const bool bf  = probe_bf16(x);
    const int wave = threadIdx.x >> 6;
    const int lane = threadIdx.x & 63;

    // h2n in registers; element map: elem = 8*lane + 512*k + t  (matches u16x8/f32x8 rows)
    float hreg[32];
    {
        const f32x8* hv = (const f32x8*)h2n;
        #pragma unroll
        for (int k = 0; k < 4; ++k) {
            f32x8 hh = hv[lane + 64 * k];
            #pragma unroll
            for (int t = 0; t < 8; ++t) hreg[8 * k + t] = hh[t];
        }
    }

    const int base = blockIdx.x * ROWS_PER_BLOCK + wave * ROWS_PER_WAVE;
    float m = NEG_BIG, s = 0.f;

    if (bf) {
        // 4 pairs of rows; per pair: 8 hoisted nontemporal 16B loads, 2 independent FMA
        // chains, 2 interleaved butterflies, uniform (all-lane) online-softmax update.
        #pragma unroll
        for (int p = 0; p < 4; ++p) {
            const int r0 = base + 2 * p, r1 = r0 + 1;
            const int c0 = min(r0, V_DIM - 1), c1 = min(r1, V_DIM - 1);
            const u16x8* w0 = (const u16x8*)W + (size_t)c0 * (H_DIM / 8) + lane;
            const u16x8* w1 = (const u16x8*)W + (size_t)c1 * (H_DIM / 8) + lane;
            u16x8 a0[4], a1[4];
            #pragma unroll
            for (int k = 0; k < 4; ++k) { a0[k] = ntl(w0 + 64 * k); a1[k] = ntl(w1 + 64 * k); }
            float acc0 = 0.f, acc1 = 0.f;
            #pragma unroll
            for (int k = 0; k < 4; ++k)
                #pragma unroll
                for (int t = 0; t < 8; ++t) {
                    float hval = hreg[8 * k + t];
                    acc0 += bf2f(a0[k][t]) * hval;
                    acc1 += bf2f(a1[k][t]) * hval;
                }
            #pragma unroll
            for (int d = 32; d; d >>= 1) {
                acc0 += __shfl_xor(acc0, d, 64);
                acc1 += __shfl_xor(acc1, d, 64);
            }
            const float l0 = acc0 + ld_scalar(b, c0, true);
            const float l1 = acc1 + ld_scalar(b, c1, true);
            const bool v0 = (r0 < V_DIM), v1 = (r1 < V_DIM);
            if (lane == 0) {
                if (v0) logits[r0] = l0;
                if (v1) logits[r1] = l1;
            }
            const float mx = fmaxf(v0 ? l0 : NEG_BIG, v1 ? l1 : NEG_BIG);
            if (mx > -1e29f) {                       // uniform across the wave
                const float mn = fmaxf(m, mx);
                s = s * __expf(m - mn)
                  + (v0 ? __expf(l0 - mn) : 0.f)
                  + (v1 ? __expf(l1 - mn) : 0.f);
                m = mn;
            }
        }
    } else {
        #pragma unroll
        for (int rr = 0; rr < ROWS_PER_WAVE; ++rr) {
            const int r = base + rr;
            const int cr = min(r, V_DIM - 1);
            const f32x8* wr = (const f32x8*)W + (size_t)cr * (H_DIM / 8) + lane;
            f32x8 a[4];
            #pragma unroll
            for (int k = 0; k < 4; ++k) a[k] = ntl(wr + 64 * k);
            float acc = 0.f;
            #pragma unroll
            for (int k = 0; k < 4; ++k)
                #pragma unroll
                for (int t = 0; t < 8; ++t) acc += a[k][t] * hreg[8 * k + t];
            acc = wave_allreduce_sum(acc);
            const float lg = acc + ((const float*)b)[cr];
            const bool v = (r < V_DIM);
            if (lane == 0 && v) logits[r] = lg;
            if (v) {
                const float mn = fmaxf(m, lg);
                s = s * __expf(m - mn) + __expf(lg - mn);
                m = mn;
            }
        }
    }

    __shared__ float wm[4], wsv[4];
    if (lane == 0) { wm[wave] = m; wsv[wave] = s; }
    __syncthreads();
    if (threadIdx.x == 0) {
        float M = fmaxf(fmaxf(wm[0], wm[1]), fmaxf(wm[2], wm[3]));
        float S = 0.f;
        #pragma unroll
        for (int w = 0; w < 4; ++w) S += wsv[w] * __expf(wm[w] - M);  // empty wave: 0*exp(very neg)=0
        pmax[blockIdx.x] = M;
        psum[blockIdx.x] = S;
    }
}

// ---------------- finalize: partials -> logZ; out = (logits - logZ) in probed dtype ----------------
__global__ __launch_bounds__(256) void finalize_kernel(
    const void* __restrict__ x,          // probe only
    const float* __restrict__ logits, const float* __restrict__ pmax,
    const float* __restrict__ psum, int nblk,
    void* __restrict__ out)
{
    const bool bf = probe_bf16(x);
    __shared__ float sm[256], ss[256];
    float m = NEG_BIG, s = 0.f;
    for (int i = threadIdx.x; i < nblk; i += 256) {
        float bm = pmax[i], bs = psum[i];
        float mn = fmaxf(m, bm);
        s = s * __expf(m - mn) + bs * __expf(bm - mn);
        m = mn;
    }
    sm[threadIdx.x] = m; ss[threadIdx.x] = s;
    __syncthreads();
    #pragma unroll
    for (int stride = 128; stride > 0; stride >>= 1) {
        if ((int)threadIdx.x < stride) {
            float m1 = sm[threadIdx.x], s1 = ss[threadIdx.x];
            float m2 = sm[threadIdx.x + stride], s2 = ss[threadIdx.x + stride];
            float mn = fmaxf(m1, m2);
            sm[threadIdx.x] = mn;
            ss[threadIdx.x] = s1 * __expf(m1 - mn) + s2 * __expf(m2 - mn);
        }
        __syncthreads();
    }
    const float logZ = sm[0] + __logf(ss[0]);
    const int i = blockIdx.x * 256 + threadIdx.x;
    if (i < V_DIM) {
        float v = logits[i] - logZ;
        if (bf) ((u16*)out)[i] = f2bf(v);
        else    ((float*)out)[i] = v;
    }
}

extern "C" void kernel_launch(void* const* d_in, const int* in_sizes, int n_in,
                              void* d_out, int out_size, void* d_ws, size_t ws_size,
                              hipStream_t stream)
{
    const void* x     = d_in[0];
    const void* h1    = d_in[1];
    const void* c1    = d_in[2];
    const void* h2    = d_in[3];
    const void* c2    = d_in[4];
    const void* W_ih1 = d_in[5];
    const void* W_hh1 = d_in[6];
    const void* b_ih1 = d_in[7];
    const void* b_hh1 = d_in[8];
    const void* W_ih2 = d_in[9];
    const void* W_hh2 = d_in[10];
    const void* b_ih2 = d_in[11];
    const void* b_hh2 = d_in[12];
    const void* W_out = d_in[13];
    const void* b_out = d_in[14];

    float* ws     = (float*)d_ws;
    float* h1n    = ws;                    // 2048 fp32
    float* h2n    = ws + 2048;             // 2048 fp32
    float* logits = ws + 4096;             // 50257 fp32 (padded to 50264)
    float* pmax   = ws + 4096 + 50264;     // 1571 fp32 (padded to 1576)
    float* psum   = pmax + 1576;           // 1571 fp32 (padded to 1576)

    const int nblk3 = (V_DIM + ROWS_PER_BLOCK - 1) / ROWS_PER_BLOCK;  // 1571

    lstm1_kernel<<<H_DIM, 256, 0, stream>>>(x, h1, c1, W_ih1, W_hh1, b_ih1, b_hh1, h1n);
    lstm2_kernel<<<H_DIM, 256, 0, stream>>>(x, h1n, h2, c2, W_ih2, W_hh2, b_ih2, b_hh2, h2n);
    logits_kernel<<<nblk3, 256, 0, stream>>>(x, h2n, W_out, b_out, logits, pmax, psum);
    finalize_kernel<<<(V_DIM + 255) / 256, 256, 0, stream>>>(x, logits, pmax, psum, nblk3, d_out);
}